// Round 11
// baseline (269.021 us; speedup 1.0000x reference)
//
#include <hip/hip_runtime.h>
#include <math.h>

// SimpleMamba: s_t = A*s_{t-1} + B*x_t ; y_t = tanh(C*s_t), per-channel.
// L=8192, D=2048, f32.
//
// R11: *** DIAGNOSTIC ROUND *** — kernels are R7's incumbent (best, 48.4 us),
// but each phase's work is repeated idempotently (p1 x8, p2 x24, p3 x3) so each
// dispatch exceeds the harness's ~41 us poison-fills and appears in the rocprof
// top-5 with its own counters. Every per-phase number so far was inferred from
// totals; R8/R10 geometry predictions both failed, so measure before theorizing.
// Repeats re-load memory for real (opaque zero offset via asm volatile defeats
// CSE/hoisting) and re-store identical values -> output bit-identical to R7.
// dur_us this round is sacrificial; the per-phase split/BW/VALU/occupancy is
// the product.
//
// CL=32 pinned by f32 overflow (A^32>0 even power; loc finite; no inf-inf NaN).
// Carry chain flat-serial (tree compose IS inf-inf NaN-unsafe for |A|>1).

#define LL 8192
#define DD 2048
#define CL 32
#define NC (LL / CL)   // 256 chunks
#define G4 (DD / 4)    // 512 float4 channel-groups per row

#define REP1 8
#define REP2 24
#define REP3 3

typedef float f32x4 __attribute__((ext_vector_type(4)));

__device__ __forceinline__ float fast_tanh(float z)
{
    float e = __builtin_amdgcn_exp2f(z * 2.885390081777927f);
    return 1.0f - 2.0f * __builtin_amdgcn_rcpf(e + 1.0f);
}

__device__ __forceinline__ int opaque_zero()
{
    int off;
    asm volatile("v_mov_b32 %0, 0" : "=v"(off));   // compiler can't prove it's 0
    return off;
}

// ---------------- Phase 1 (x REP1): per-chunk local end-state ----------------
__global__ __launch_bounds__(256) void mamba_p1(
    const float4* __restrict__ x4, const float4* __restrict__ A4,
    const float4* __restrict__ B4, float4* __restrict__ loc4)
{
    int lin   = blockIdx.x * 256 + threadIdx.x;
    int chunk = lin >> 9;
    int grp   = lin & (G4 - 1);

    float4 a = A4[grp];
    float4 b = B4[grp];

    for (int r = 0; r < REP1; ++r) {
        const float4* xp = x4 + (size_t)chunk * CL * G4 + grp + opaque_zero();
        float sx = 0.f, sy = 0.f, sz = 0.f, sw = 0.f;
        #pragma unroll
        for (int t0 = 0; t0 < CL; t0 += 16) {
            float4 v[16];
            #pragma unroll
            for (int k = 0; k < 16; ++k)
                v[k] = xp[(size_t)(t0 + k) * G4];
            #pragma unroll
            for (int k = 0; k < 16; ++k) {
                sx = fmaf(a.x, sx, b.x * v[k].x);
                sy = fmaf(a.y, sy, b.y * v[k].y);
                sz = fmaf(a.z, sz, b.z * v[k].z);
                sw = fmaf(a.w, sw, b.w * v[k].w);
            }
        }
        loc4[(size_t)chunk * G4 + grp] = make_float4(sx, sy, sz, sw);
    }
}

// ---------------- Phase 2 (x REP2): serial carry scan, thread per channel ----------------
__global__ __launch_bounds__(64) void mamba_p2(
    const float* __restrict__ A, const float* __restrict__ loc,
    float* __restrict__ car)
{
    int ch = blockIdx.x * 64 + threadIdx.x;
    float p = A[ch];
    #pragma unroll
    for (int i = 0; i < 5; ++i) p *= p;            // A^32 > 0, finite

    for (int r = 0; r < REP2; ++r) {
        const float* locp = loc + opaque_zero();   // force real re-loads per rep
        float c = 0.f;
        for (int c0 = 0; c0 < NC; c0 += 64) {
            float lv[64];
            #pragma unroll
            for (int k = 0; k < 64; ++k)
                lv[k] = locp[(size_t)(c0 + k) * DD + ch];
            #pragma unroll
            for (int k = 0; k < 64; ++k) {
                car[(size_t)(c0 + k) * DD + ch] = c;
                c = fmaf(p, c, lv[k]);             // loc finite, p>0: no inf-inf
            }
        }
    }
}

// ---------------- Phase 3 (x REP3): recompute from carry, emit tanh(C*s) ----------------
__global__ __launch_bounds__(256) void mamba_p3(
    const float4* __restrict__ x4, const float4* __restrict__ A4,
    const float4* __restrict__ B4, const float4* __restrict__ C4,
    const float4* __restrict__ car4, float4* __restrict__ y4)
{
    int lin   = blockIdx.x * 256 + threadIdx.x;
    int chunk = lin >> 9;
    int grp   = lin & (G4 - 1);

    float4 a = A4[grp];
    float4 b = B4[grp];
    float4 c = C4[grp];

    for (int r = 0; r < REP3; ++r) {
        const float4* xp = x4 + (size_t)chunk * CL * G4 + grp + opaque_zero();
        float4*       yp = y4 + (size_t)chunk * CL * G4 + grp;
        float4 s0 = car4[(size_t)chunk * G4 + grp + opaque_zero()];
        float sx = s0.x, sy = s0.y, sz = s0.z, sw = s0.w;

        #pragma unroll
        for (int t0 = 0; t0 < CL; t0 += 8) {
            float4 v[8];
            #pragma unroll
            for (int k = 0; k < 8; ++k)
                v[k] = xp[(size_t)(t0 + k) * G4];
            #pragma unroll
            for (int k = 0; k < 8; ++k) {
                sx = fmaf(a.x, sx, b.x * v[k].x);
                sy = fmaf(a.y, sy, b.y * v[k].y);
                sz = fmaf(a.z, sz, b.z * v[k].z);
                sw = fmaf(a.w, sw, b.w * v[k].w);
                f32x4 o;
                o.x = fast_tanh(c.x * sx);
                o.y = fast_tanh(c.y * sy);
                o.z = fast_tanh(c.z * sz);
                o.w = fast_tanh(c.w * sw);
                __builtin_nontemporal_store(o, (f32x4*)&yp[(size_t)(t0 + k) * G4]);
            }
        }
    }
}

extern "C" void kernel_launch(void* const* d_in, const int* in_sizes, int n_in,
                              void* d_out, int out_size, void* d_ws, size_t ws_size,
                              hipStream_t stream)
{
    const float4* x4 = (const float4*)d_in[0];
    const float*  Af = (const float*)d_in[1];
    const float4* A4 = (const float4*)d_in[1];
    const float4* B4 = (const float4*)d_in[2];
    const float4* C4 = (const float4*)d_in[3];
    float4* y4 = (float4*)d_out;

    float*  locf = (float*)d_ws;
    float4* loc4 = (float4*)d_ws;
    float*  carf = locf + (size_t)NC * DD;
    float4* car4 = (float4*)carf;

    const int nthreads = NC * G4;
    mamba_p1<<<nthreads / 256, 256, 0, stream>>>(x4, A4, B4, loc4);
    mamba_p2<<<DD / 64, 64, 0, stream>>>(Af, locf, carf);
    mamba_p3<<<nthreads / 256, 256, 0, stream>>>(x4, A4, B4, C4, car4, y4);
}